// Round 1
// 231.121 us; speedup vs baseline: 1.1080x; 1.1080x over previous
//
#include <hip/hip_runtime.h>
#include <hip/hip_bf16.h>

typedef short v8s __attribute__((ext_vector_type(8)));
typedef short v4s __attribute__((ext_vector_type(4)));
typedef float v4f __attribute__((ext_vector_type(4)));

#define BS 4
#define SEQ 2048
#define DMODEL 768
#define HEADS 12
#define GROUPS 2
#define DK 64
#define LOG2E 1.4426950408889634f

static __device__ __forceinline__ short f2bs(float f) {
    __hip_bfloat16 h = __float2bfloat16(f);
    return *reinterpret_cast<short*>(&h);
}

static __device__ __forceinline__ float fast_exp2(float x) {
#if __has_builtin(__builtin_amdgcn_exp2f)
    return __builtin_amdgcn_exp2f(x);
#else
    return __expf(x * 0.6931471805599453f);
#endif
}

// Async global->LDS, 16B per lane. LDS dest is WAVE-UNIFORM base; lane i's
// 16B lands at base + i*16 (m97 semantics). Requires unpadded lane-contiguous
// LDS chunks; swizzling is done by permuting the GLOBAL source address.
static __device__ __forceinline__ void gld16(const short* g, short* l) {
    __builtin_amdgcn_global_load_lds(
        (__attribute__((address_space(1))) void*)(g),
        (__attribute__((address_space(3))) void*)(l), 16, 0, 0);
}

struct alignas(8) s4pack { short a, b, c, d; };

#define FENCE() asm volatile("" ::: "memory")
#define WAIT_VM0() asm volatile("s_waitcnt vmcnt(0)" ::: "memory")
#define WAIT_LGKM0() asm volatile("s_waitcnt lgkmcnt(0)" ::: "memory")
#define WAIT_VM0_LGKM0() asm volatile("s_waitcnt vmcnt(0) lgkmcnt(0)" ::: "memory")
#define BARRIER() do { FENCE(); __builtin_amdgcn_s_barrier(); FENCE(); } while (0)

// ---------------------------------------------------------------------------
// q fp32 -> bf16. grid 1536 x 256.
// ---------------------------------------------------------------------------
__global__ __launch_bounds__(256) void convert_q(
    const float* __restrict__ q, short* __restrict__ qbf)
{
    const size_t base = (size_t)blockIdx.x * 4096;
#pragma unroll
    for (int r = 0; r < 4; ++r) {
        const size_t i = base + r * 1024 + threadIdx.x * 4;
        const float4 a = *reinterpret_cast<const float4*>(q + i);
        s4pack p{f2bs(a.x), f2bs(a.y), f2bs(a.z), f2bs(a.w)};
        *reinterpret_cast<s4pack*>(qbf + i) = p;
    }
}

// ---------------------------------------------------------------------------
// Fused weight transpose + fp32->bf16. z: 0=Wq 1=Wo 2=Wk 3=Wv. grid (24,24,4).
// ---------------------------------------------------------------------------
__global__ __launch_bounds__(256) void wtrans_all(
    const float* __restrict__ Wq, const float* __restrict__ Wk,
    const float* __restrict__ Wv, const float* __restrict__ Wo,
    short* __restrict__ WqT, short* __restrict__ WkT,
    short* __restrict__ WvT, short* __restrict__ WoT)
{
    const int z = blockIdx.z;
    const float* W;
    short* WT;
    int N;
    if (z == 0)      { W = Wq; WT = WqT; N = 768; }
    else if (z == 1) { W = Wo; WT = WoT; N = 768; }
    else if (z == 2) { W = Wk; WT = WkT; N = 128; }
    else             { W = Wv; WT = WvT; N = 128; }
    const int n0 = blockIdx.x * 32, k0 = blockIdx.y * 32;
    if (n0 >= N) return;

    __shared__ float t[32][33];
    const int lx = threadIdx.x & 31, ly = threadIdx.x >> 5;
#pragma unroll
    for (int r = 0; r < 4; ++r)
        t[ly + r * 8][lx] = W[(size_t)(k0 + ly + r * 8) * N + n0 + lx];
    __syncthreads();
#pragma unroll
    for (int r = 0; r < 4; ++r)
        WT[(size_t)(n0 + ly + r * 8) * DMODEL + k0 + lx] = f2bs(t[lx][ly + r * 8]);
}

// ---------------------------------------------------------------------------
// Unified projection: BM=BN=128, BK=64, double-buffered [128][64] LDS tiles,
// 2-phase single-barrier pipeline (T3-min), XOR granule swizzle (T2 via
// pre-swizzled global source), setprio around MFMA (T5).
// grid (64, 8): y<6 Q slice y (*log2e); y==6 K; y==7 V (transposed +
// s-permuted within 64-token blocks for attn's K=32 PV).
// ---------------------------------------------------------------------------
__global__ __launch_bounds__(256) void proj_all(
    const short* __restrict__ qbf, const float* __restrict__ kin,
    const float* __restrict__ vin,
    const short* __restrict__ WqT, const short* __restrict__ WkT,
    const short* __restrict__ WvT,
    const float* __restrict__ bq, const float* __restrict__ bk,
    const float* __restrict__ bv,
    short* __restrict__ Qp, short* __restrict__ Kp, short* __restrict__ Vt)
{
    __shared__ short lA[2][128 * 64];
    __shared__ short lB[2][128 * 64];

    const int y = blockIdx.y;
    const short* WT = (y < 6) ? WqT + (size_t)y * 128 * DMODEL
                              : (y == 6) ? WkT : WvT;
    const float* bias = (y < 6) ? bq + y * 128 : (y == 6) ? bk : bv;

    const int tid  = threadIdx.x;
    const int lane = tid & 63;
    const int wid  = tid >> 6;
    const int l16  = lane & 15;
    const int quad = lane >> 4;
    const int wm   = wid & 1;
    const int wn   = wid >> 1;
    const int bm   = blockIdx.x;

    v4f acc[4][4];
#pragma unroll
    for (int i = 0; i < 4; ++i)
#pragma unroll
        for (int j = 0; j < 4; ++j) acc[i][j] = (v4f){0.f, 0.f, 0.f, 0.f};

    // gld16 chunk addressing: 1KB chunk = 8 rows x 128B. Lane i lands at LDS
    // (row=c*8+(i>>3), granule=i&7); fetch global granule (i&7)^(i>>3) so that
    // LDS[row][g] holds global[row][g ^ (row&7)].
    const int crow = lane >> 3;
    const int ccol = ((lane & 7) ^ crow) << 3;   // shorts

    float4 areg[8];

    const float* Afp = (y == 6) ? kin : vin;

    // --- staging helpers ---
    auto stageA_bf = [&](int kt, int pb) {
        const short* Ag = qbf + (size_t)bm * 128 * DMODEL + kt * 64;
#pragma unroll
        for (int c = wid; c < 16; c += 4)
            gld16(Ag + (size_t)(c * 8 + crow) * DMODEL + ccol, &lA[pb][c * 512]);
    };
    auto stageB = [&](int kt, int pb) {
        const short* Bg = WT + kt * 64;
#pragma unroll
        for (int c = wid; c < 16; c += 4)
            gld16(Bg + (size_t)(c * 8 + crow) * DMODEL + ccol, &lB[pb][c * 512]);
    };
    auto loadA_f32 = [&](int kt) {
#pragma unroll
        for (int r = 0; r < 8; ++r) {
            const int f4 = tid + 256 * r;
            const int row = f4 >> 4;
            const int q4 = f4 & 15;
            areg[r] = *reinterpret_cast<const float4*>(
                Afp + (size_t)(bm * 128 + row) * DMODEL + kt * 64 + q4 * 4);
        }
    };
    auto writeA_f32 = [&](int pb) {
#pragma unroll
        for (int r = 0; r < 8; ++r) {
            const int f4 = tid + 256 * r;
            const int row = f4 >> 4;
            const int q4 = f4 & 15;
            const int gran = q4 >> 1, half = q4 & 1;
            const int scol = ((gran ^ (row & 7)) << 3) + (half << 2);
            s4pack p{f2bs(areg[r].x), f2bs(areg[r].y), f2bs(areg[r].z), f2bs(areg[r].w)};
            *reinterpret_cast<s4pack*>(&lA[pb][row * 64 + scol]) = p;
        }
    };
    auto compute = [&](int cur) {
#pragma unroll
        for (int kk = 0; kk < 2; ++kk) {
            const int fcol = (((kk << 2) + quad) ^ (l16 & 7)) << 3;
            v8s af[4], bf[4];
#pragma unroll
            for (int i = 0; i < 4; ++i)
                af[i] = *reinterpret_cast<const v8s*>(&lA[cur][(wm * 64 + i * 16 + l16) * 64 + fcol]);
#pragma unroll
            for (int j = 0; j < 4; ++j)
                bf[j] = *reinterpret_cast<const v8s*>(&lB[cur][(wn * 64 + j * 16 + l16) * 64 + fcol]);
            __builtin_amdgcn_s_setprio(1);
#pragma unroll
            for (int i = 0; i < 4; ++i)
#pragma unroll
                for (int j = 0; j < 4; ++j)
                    acc[i][j] = __builtin_amdgcn_mfma_f32_16x16x32_bf16(af[i], bf[j], acc[i][j], 0, 0, 0);
            __builtin_amdgcn_s_setprio(0);
        }
    };

    if (y < 6) {
        stageA_bf(0, 0);
        stageB(0, 0);
        WAIT_VM0();
        BARRIER();
        for (int kt = 0; kt < 12; ++kt) {
            const int cur = kt & 1;
            if (kt < 11) { stageA_bf(kt + 1, cur ^ 1); stageB(kt + 1, cur ^ 1); }
            compute(cur);
            WAIT_VM0();
            BARRIER();
        }
    } else {
        loadA_f32(0);
        writeA_f32(0);
        stageB(0, 0);
        WAIT_VM0_LGKM0();
        BARRIER();
        for (int kt = 0; kt < 12; ++kt) {
            const int cur = kt & 1;
            if (kt < 11) { loadA_f32(kt + 1); stageB(kt + 1, cur ^ 1); }
            compute(cur);
            if (kt < 11) writeA_f32(cur ^ 1);
            WAIT_VM0_LGKM0();
            BARRIER();
        }
    }

#pragma unroll
    for (int i = 0; i < 4; ++i) {
#pragma unroll
        for (int j = 0; j < 4; ++j) {
            const int Cl = wn * 64 + j * 16 + l16;   // 0..127 within slice
            const float bvv = bias[Cl];
#pragma unroll
            for (int reg = 0; reg < 4; ++reg) {
                const int R = bm * 128 + wm * 64 + i * 16 + quad * 4 + reg;
                const int b = R >> 11;
                const int s = R & 2047;
                if (y < 6) {
                    const int C = y * 128 + Cl;
                    const int h = C >> 6, d = C & 63;
                    Qp[((size_t)(b * HEADS + h) * SEQ + s) * DK + d] =
                        f2bs((acc[i][j][reg] + bvv) * LOG2E);
                } else if (y == 6) {
                    const int g = Cl >> 6, d = Cl & 63;
                    Kp[((size_t)(b * GROUPS + g) * SEQ + s) * DK + d] =
                        f2bs(acc[i][j][reg] + bvv);
                } else {
                    const int g = Cl >> 6, d = Cl & 63;
                    const int s2 = (s & ~63) | (s & 0x23) | ((s & 0x0C) << 1) | ((s & 0x10) >> 2);
                    Vt[((size_t)(b * GROUPS + g) * DK + d) * SEQ + s2] =
                        f2bs(acc[i][j][reg] + bvv);
                }
            }
        }
    }
}

// ---------------------------------------------------------------------------
// Flash attention: no-max softmax, S^T trick, K=32 PV on pre-permuted V.
// New: T14 async-STAGE split (issue K/V global loads for tile kt+1 into regs
// before compute of tile kt; LDS writes between raw s_barriers with only
// lgkmcnt(0) — loads stay in flight across barriers), T5 setprio.
// ---------------------------------------------------------------------------
__global__ __launch_bounds__(256) void attn_kernel(
    const short* __restrict__ Qp, const short* __restrict__ Kp,
    const short* __restrict__ Vt, short* __restrict__ Oat)
{
    const int LSK = 72;
    const int LSV = 136;
    __shared__ short lK[128 * 72];
    __shared__ short lV[64 * 136];

    const int qt = blockIdx.x, h = blockIdx.y, b = blockIdx.z;
    const int g = h & 1;
    const int tid  = threadIdx.x;
    const int lane = tid & 63;
    const int wid  = tid >> 6;
    const int l16  = lane & 15;
    const int quad = lane >> 4;

    v8s qf[2][2];
#pragma unroll
    for (int mi = 0; mi < 2; ++mi) {
        const size_t qbase =
            ((size_t)(b * HEADS + h) * SEQ + qt * 128 + wid * 32 + mi * 16 + l16) * DK;
        qf[mi][0] = *reinterpret_cast<const v8s*>(Qp + qbase + quad * 8);
        qf[mi][1] = *reinterpret_cast<const v8s*>(Qp + qbase + quad * 8 + 32);
    }

    const size_t kbase = (size_t)(b * GROUPS + g) * SEQ * DK;
    const size_t vbase = (size_t)(b * GROUPS + g) * DK * SEQ;

    const short one = (short)0x3F80;
    const v8s ones8 = {one, one, one, one, one, one, one, one};

    v4f oacc[2][5];
#pragma unroll
    for (int mi = 0; mi < 2; ++mi)
#pragma unroll
        for (int n = 0; n < 5; ++n) oacc[mi][n] = (v4f){0.f, 0.f, 0.f, 0.f};

    v8s kreg[4], vreg[4];

    auto issue_loads = [&](int kt) {
#pragma unroll
        for (int r = 0; r < 4; ++r) {
            const int idx = tid + 256 * r;
            const int rowK = idx >> 3, cK = (idx & 7) << 3;
            kreg[r] = *reinterpret_cast<const v8s*>(
                Kp + kbase + (size_t)(kt * 128 + rowK) * DK + cK);
            const int rowV = idx >> 4, cV = (idx & 15) << 3;
            vreg[r] = *reinterpret_cast<const v8s*>(
                Vt + vbase + (size_t)rowV * SEQ + kt * 128 + cV);
        }
    };
    auto write_lds = [&]() {
#pragma unroll
        for (int r = 0; r < 4; ++r) {
            const int idx = tid + 256 * r;
            const int rowK = idx >> 3, cK = (idx & 7) << 3;
            *reinterpret_cast<v8s*>(&lK[rowK * LSK + cK]) = kreg[r];
            const int rowV = idx >> 4, cV = (idx & 15) << 3;
            *reinterpret_cast<v8s*>(&lV[rowV * LSV + cV]) = vreg[r];
        }
    };

    issue_loads(0);
    for (int kt = 0; kt < 16; ++kt) {
        if (kt) BARRIER();            // readers of tile kt-1 done (no vmcnt drain)
        write_lds();                  // consumes kreg/vreg (compiler vmcnt waits)
        if (kt < 15) issue_loads(kt + 1);  // in flight across barrier + compute
        WAIT_LGKM0();                 // ds_writes visible before barrier
        BARRIER();

#pragma unroll
        for (int kt2 = 0; kt2 < 2; ++kt2) {
            v4s pp[2][4];
#pragma unroll
            for (int j = 0; j < 4; ++j) {
                const v8s kf0 = *reinterpret_cast<const v8s*>(
                    &lK[(kt2 * 64 + j * 16 + l16) * LSK + quad * 8]);
                const v8s kf1 = *reinterpret_cast<const v8s*>(
                    &lK[(kt2 * 64 + j * 16 + l16) * LSK + quad * 8 + 32]);
#pragma unroll
                for (int mi = 0; mi < 2; ++mi) {
                    v4f z = (v4f){0.f, 0.f, 0.f, 0.f};
                    __builtin_amdgcn_s_setprio(1);
                    z = __builtin_amdgcn_mfma_f32_16x16x32_bf16(kf0, qf[mi][0], z, 0, 0, 0);
                    z = __builtin_amdgcn_mfma_f32_16x16x32_bf16(kf1, qf[mi][1], z, 0, 0, 0);
                    __builtin_amdgcn_s_setprio(0);
                    v4s p;
#pragma unroll
                    for (int reg = 0; reg < 4; ++reg) p[reg] = f2bs(fast_exp2(z[reg]));
                    pp[mi][j] = p;
                }
            }

#pragma unroll
            for (int cj = 0; cj < 2; ++cj) {
                v8s pf[2];
#pragma unroll
                for (int mi = 0; mi < 2; ++mi)
                    pf[mi] = __builtin_shufflevector(pp[mi][2 * cj], pp[mi][2 * cj + 1],
                                                     0, 1, 2, 3, 4, 5, 6, 7);
                __builtin_amdgcn_s_setprio(1);
#pragma unroll
                for (int n = 0; n < 4; ++n) {
                    const v8s vf = *reinterpret_cast<const v8s*>(
                        &lV[(n * 16 + l16) * LSV + kt2 * 64 + cj * 32 + quad * 8]);
#pragma unroll
                    for (int mi = 0; mi < 2; ++mi)
                        oacc[mi][n] = __builtin_amdgcn_mfma_f32_16x16x32_bf16(pf[mi], vf, oacc[mi][n], 0, 0, 0);
                }
#pragma unroll
                for (int mi = 0; mi < 2; ++mi)
                    oacc[mi][4] = __builtin_amdgcn_mfma_f32_16x16x32_bf16(pf[mi], ones8, oacc[mi][4], 0, 0, 0);
                __builtin_amdgcn_s_setprio(0);
            }
        }
    }

#pragma unroll
    for (int mi = 0; mi < 2; ++mi) {
        float rdiv[4];
#pragma unroll
        for (int reg = 0; reg < 4; ++reg)
            rdiv[reg] = __builtin_amdgcn_rcpf(oacc[mi][4][reg]);
#pragma unroll
        for (int n = 0; n < 4; ++n)
#pragma unroll
            for (int reg = 0; reg < 4; ++reg) {
                const int qrow = qt * 128 + wid * 32 + mi * 16 + quad * 4 + reg;
                Oat[(size_t)(b * SEQ + qrow) * DMODEL + h * 64 + n * 16 + l16] =
                    f2bs(oacc[mi][n][reg] * rdiv[reg]);
            }
    }
}

// ---------------------------------------------------------------------------
// Output GEMM: BM=64, BN=128, BK=64, double-buffered LDS, 2-phase single
// barrier, XOR granule swizzle. grid (128, 6) = 768 blocks = 3/CU. out fp32.
// ---------------------------------------------------------------------------
__global__ __launch_bounds__(256) void out_gemm(
    const short* __restrict__ A, const short* __restrict__ WT,
    const float* __restrict__ bias, float* __restrict__ out)
{
    __shared__ short lA[2][64 * 64];
    __shared__ short lB[2][128 * 64];

    const int tid  = threadIdx.x;
    const int lane = tid & 63;
    const int wid  = tid >> 6;
    const int l16  = lane & 15;
    const int quad = lane >> 4;
    const int wm   = wid & 1;
    const int wn   = wid >> 1;
    const int bm   = blockIdx.x;
    const int bn   = blockIdx.y;

    v4f acc[2][4];
#pragma unroll
    for (int i = 0; i < 2; ++i)
#pragma unroll
        for (int j = 0; j < 4; ++j) acc[i][j] = (v4f){0.f, 0.f, 0.f, 0.f};

    const int crow = lane >> 3;
    const int ccol = ((lane & 7) ^ crow) << 3;
    const short* Abase = A + (size_t)bm * 64 * DMODEL;
    const short* Bbase = WT + (size_t)bn * 128 * DMODEL;

    auto stage = [&](int kt, int pb) {
#pragma unroll
        for (int c = wid; c < 8; c += 4)
            gld16(Abase + (size_t)(c * 8 + crow) * DMODEL + kt * 64 + ccol, &lA[pb][c * 512]);
#pragma unroll
        for (int c = wid; c < 16; c += 4)
            gld16(Bbase + (size_t)(c * 8 + crow) * DMODEL + kt * 64 + ccol, &lB[pb][c * 512]);
    };
    auto compute = [&](int cur) {
#pragma unroll
        for (int kk = 0; kk < 2; ++kk) {
            const int fcol = (((kk << 2) + quad) ^ (l16 & 7)) << 3;
            v8s af[2], bf[4];
#pragma unroll
            for (int i = 0; i < 2; ++i)
                af[i] = *reinterpret_cast<const v8s*>(&lA[cur][(wm * 32 + i * 16 + l16) * 64 + fcol]);
#pragma unroll
            for (int j = 0; j < 4; ++j)
                bf[j] = *reinterpret_cast<const v8s*>(&lB[cur][(wn * 64 + j * 16 + l16) * 64 + fcol]);
            __builtin_amdgcn_s_setprio(1);
#pragma unroll
            for (int i = 0; i < 2; ++i)
#pragma unroll
                for (int j = 0; j < 4; ++j)
                    acc[i][j] = __builtin_amdgcn_mfma_f32_16x16x32_bf16(af[i], bf[j], acc[i][j], 0, 0, 0);
            __builtin_amdgcn_s_setprio(0);
        }
    };

    stage(0, 0);
    WAIT_VM0();
    BARRIER();
    for (int kt = 0; kt < 12; ++kt) {
        const int cur = kt & 1;
        if (kt < 11) stage(kt + 1, cur ^ 1);
        compute(cur);
        WAIT_VM0();
        BARRIER();
    }

#pragma unroll
    for (int i = 0; i < 2; ++i)
#pragma unroll
        for (int j = 0; j < 4; ++j) {
            const int C = bn * 128 + wn * 64 + j * 16 + l16;
            const float bv = bias[C];
#pragma unroll
            for (int reg = 0; reg < 4; ++reg) {
                const int R = bm * 64 + wm * 32 + i * 16 + quad * 4 + reg;
                out[(size_t)R * DMODEL + C] = acc[i][j][reg] + bv;
            }
        }
}

extern "C" void kernel_launch(void* const* d_in, const int* in_sizes, int n_in,
                              void* d_out, int out_size, void* d_ws, size_t ws_size,
                              hipStream_t stream) {
    const float* q  = (const float*)d_in[0];
    const float* k  = (const float*)d_in[1];
    const float* v  = (const float*)d_in[2];
    const float* Wq = (const float*)d_in[3];
    const float* bq = (const float*)d_in[4];
    const float* Wk = (const float*)d_in[5];
    const float* bk = (const float*)d_in[6];
    const float* Wv = (const float*)d_in[7];
    const float* bv = (const float*)d_in[8];
    const float* Wo = (const float*)d_in[9];
    const float* bo = (const float*)d_in[10];

    short* WqT = (short*)d_ws;                              // 589824
    short* WkT = WqT + 589824;                              // 98304
    short* WvT = WkT + 98304;                               // 98304
    short* WoT = WvT + 98304;                               // 589824
    short* qbf = WoT + 589824;                              // 6291456
    short* Qp  = qbf + 6291456;                             // [b,h,s,d]  6291456
    short* Kp  = Qp + (size_t)BS * HEADS * SEQ * DK;        // [b,g,s,d]  1048576
    short* Vt  = Kp + (size_t)BS * GROUPS * SEQ * DK;       // [b,g,d,s_perm] 1048576
    short* Oat = Vt + (size_t)BS * GROUPS * SEQ * DK;       // [b,s,h*d]  6291456

    convert_q<<<1536, 256, 0, stream>>>(q, qbf);
    wtrans_all<<<dim3(24, 24, 4), 256, 0, stream>>>(Wq, Wk, Wv, Wo, WqT, WkT, WvT, WoT);
    proj_all<<<dim3(64, 8), 256, 0, stream>>>(qbf, k, v, WqT, WkT, WvT,
                                              bq, bk, bv, Qp, Kp, Vt);
    attn_kernel<<<dim3(16, HEADS, BS), 256, 0, stream>>>(Qp, Kp, Vt, Oat);
    out_gemm<<<dim3(128, 6), 256, 0, stream>>>(Oat, WoT, bo, (float*)d_out);
}

// Round 2
// 229.826 us; speedup vs baseline: 1.1142x; 1.0056x over previous
//
#include <hip/hip_runtime.h>
#include <hip/hip_bf16.h>

typedef short v8s __attribute__((ext_vector_type(8)));
typedef short v4s __attribute__((ext_vector_type(4)));
typedef float v4f __attribute__((ext_vector_type(4)));

#define BS 4
#define SEQ 2048
#define DMODEL 768
#define HEADS 12
#define GROUPS 2
#define DK 64
#define LOG2E 1.4426950408889634f

static __device__ __forceinline__ short f2bs(float f) {
    __hip_bfloat16 h = __float2bfloat16(f);
    return *reinterpret_cast<short*>(&h);
}

static __device__ __forceinline__ float fast_exp2(float x) {
#if __has_builtin(__builtin_amdgcn_exp2f)
    return __builtin_amdgcn_exp2f(x);
#else
    return __expf(x * 0.6931471805599453f);
#endif
}

// Async global->LDS, 16B per lane. LDS dest is WAVE-UNIFORM base; lane i's
// 16B lands at base + i*16 (m97 semantics). Swizzling is done by permuting
// the GLOBAL source address (both-sides-or-neither rule).
static __device__ __forceinline__ void gld16(const short* g, short* l) {
    __builtin_amdgcn_global_load_lds(
        (__attribute__((address_space(1))) void*)(g),
        (__attribute__((address_space(3))) void*)(l), 16, 0, 0);
}

struct alignas(8) s4pack { short a, b, c, d; };

#define FENCE() asm volatile("" ::: "memory")
#define WAIT_VM0() asm volatile("s_waitcnt vmcnt(0)" ::: "memory")
#define WAIT_LGKM0() asm volatile("s_waitcnt lgkmcnt(0)" ::: "memory")
#define WAIT_VM0_LGKM0() asm volatile("s_waitcnt vmcnt(0) lgkmcnt(0)" ::: "memory")
#define BARRIER() do { FENCE(); __builtin_amdgcn_s_barrier(); FENCE(); } while (0)

// ---------------------------------------------------------------------------
// q fp32 -> bf16. grid 1536 x 256.
// ---------------------------------------------------------------------------
__global__ __launch_bounds__(256) void convert_q(
    const float* __restrict__ q, short* __restrict__ qbf)
{
    const size_t base = (size_t)blockIdx.x * 4096;
#pragma unroll
    for (int r = 0; r < 4; ++r) {
        const size_t i = base + r * 1024 + threadIdx.x * 4;
        const float4 a = *reinterpret_cast<const float4*>(q + i);
        s4pack p{f2bs(a.x), f2bs(a.y), f2bs(a.z), f2bs(a.w)};
        *reinterpret_cast<s4pack*>(qbf + i) = p;
    }
}

// ---------------------------------------------------------------------------
// Fused weight transpose + fp32->bf16. z: 0=Wq 1=Wo 2=Wk 3=Wv. grid (24,24,4).
// ---------------------------------------------------------------------------
__global__ __launch_bounds__(256) void wtrans_all(
    const float* __restrict__ Wq, const float* __restrict__ Wk,
    const float* __restrict__ Wv, const float* __restrict__ Wo,
    short* __restrict__ WqT, short* __restrict__ WkT,
    short* __restrict__ WvT, short* __restrict__ WoT)
{
    const int z = blockIdx.z;
    const float* W;
    short* WT;
    int N;
    if (z == 0)      { W = Wq; WT = WqT; N = 768; }
    else if (z == 1) { W = Wo; WT = WoT; N = 768; }
    else if (z == 2) { W = Wk; WT = WkT; N = 128; }
    else             { W = Wv; WT = WvT; N = 128; }
    const int n0 = blockIdx.x * 32, k0 = blockIdx.y * 32;
    if (n0 >= N) return;

    __shared__ float t[32][33];
    const int lx = threadIdx.x & 31, ly = threadIdx.x >> 5;
#pragma unroll
    for (int r = 0; r < 4; ++r)
        t[ly + r * 8][lx] = W[(size_t)(k0 + ly + r * 8) * N + n0 + lx];
    __syncthreads();
#pragma unroll
    for (int r = 0; r < 4; ++r)
        WT[(size_t)(n0 + ly + r * 8) * DMODEL + k0 + lx] = f2bs(t[lx][ly + r * 8]);
}

// ---------------------------------------------------------------------------
// Q projection: BM=64, BN=128, BK=64, dbuf LDS, 2-phase pipeline, XOR granule
// swizzle via pre-swizzled global source, setprio. grid (128, 6) = 768 blocks
// = 3/CU (LDS 48KB = 3/CU). Writes Qp [b,h,s,d] scaled by LOG2E.
// ---------------------------------------------------------------------------
__global__ __launch_bounds__(256) void proj_q(
    const short* __restrict__ qbf, const short* __restrict__ WqT,
    const float* __restrict__ bq, short* __restrict__ Qp)
{
    __shared__ short lA[2][64 * 64];
    __shared__ short lB[2][128 * 64];

    const int y = blockIdx.y;
    const short* WT = WqT + (size_t)y * 128 * DMODEL;
    const float* bias = bq + y * 128;

    const int tid  = threadIdx.x;
    const int lane = tid & 63;
    const int wid  = tid >> 6;
    const int l16  = lane & 15;
    const int quad = lane >> 4;
    const int wm   = wid & 1;
    const int wn   = wid >> 1;
    const int bm   = blockIdx.x;

    v4f acc[2][4];
#pragma unroll
    for (int i = 0; i < 2; ++i)
#pragma unroll
        for (int j = 0; j < 4; ++j) acc[i][j] = (v4f){0.f, 0.f, 0.f, 0.f};

    // gld16 chunk: 1KB = 8 rows x 128B. Lane i lands at (row=c*8+(i>>3),
    // granule=i&7); fetch global granule (i&7)^(i>>3) so LDS[row][g] holds
    // global[row][g ^ (row&7)].
    const int crow = lane >> 3;
    const int ccol = ((lane & 7) ^ crow) << 3;

    const short* Abase = qbf + (size_t)bm * 64 * DMODEL;

    auto stage = [&](int kt, int pb) {
#pragma unroll
        for (int c = wid; c < 8; c += 4)
            gld16(Abase + (size_t)(c * 8 + crow) * DMODEL + kt * 64 + ccol, &lA[pb][c * 512]);
#pragma unroll
        for (int c = wid; c < 16; c += 4)
            gld16(WT + (size_t)(c * 8 + crow) * DMODEL + kt * 64 + ccol, &lB[pb][c * 512]);
    };
    auto compute = [&](int cur) {
#pragma unroll
        for (int kk = 0; kk < 2; ++kk) {
            const int fcol = (((kk << 2) + quad) ^ (l16 & 7)) << 3;
            v8s af[2], bf[4];
#pragma unroll
            for (int i = 0; i < 2; ++i)
                af[i] = *reinterpret_cast<const v8s*>(&lA[cur][(wm * 32 + i * 16 + l16) * 64 + fcol]);
#pragma unroll
            for (int j = 0; j < 4; ++j)
                bf[j] = *reinterpret_cast<const v8s*>(&lB[cur][(wn * 64 + j * 16 + l16) * 64 + fcol]);
            __builtin_amdgcn_s_setprio(1);
#pragma unroll
            for (int i = 0; i < 2; ++i)
#pragma unroll
                for (int j = 0; j < 4; ++j)
                    acc[i][j] = __builtin_amdgcn_mfma_f32_16x16x32_bf16(af[i], bf[j], acc[i][j], 0, 0, 0);
            __builtin_amdgcn_s_setprio(0);
        }
    };

    stage(0, 0);
    WAIT_VM0();
    BARRIER();
    for (int kt = 0; kt < 12; ++kt) {
        const int cur = kt & 1;
        if (kt < 11) stage(kt + 1, cur ^ 1);
        compute(cur);
        WAIT_VM0();
        BARRIER();
    }

#pragma unroll
    for (int i = 0; i < 2; ++i)
#pragma unroll
        for (int j = 0; j < 4; ++j) {
            const int Cl = wn * 64 + j * 16 + l16;
            const float bvv = bias[Cl];
            const int C = y * 128 + Cl;
            const int h = C >> 6, d = C & 63;
#pragma unroll
            for (int reg = 0; reg < 4; ++reg) {
                const int R = bm * 64 + wm * 32 + i * 16 + quad * 4 + reg;
                const int b = R >> 11;
                const int s = R & 2047;
                Qp[((size_t)(b * HEADS + h) * SEQ + s) * DK + d] =
                    f2bs((acc[i][j][reg] + bvv) * LOG2E);
            }
        }
}

// ---------------------------------------------------------------------------
// K/V projection (fp32 A): BM=32, BN=128, BK=64, dbuf, 2-phase. Memory-bound
// (reads 50MB fp32). grid (256, 2) = 512 blocks = 2/CU; LDS 40KB.
// y==0: K -> Kp [b,g,s,d]; y==1: V -> Vt [b,g,d,s_perm].
// ---------------------------------------------------------------------------
__global__ __launch_bounds__(256) void proj_kv(
    const float* __restrict__ kin, const float* __restrict__ vin,
    const short* __restrict__ WkT, const short* __restrict__ WvT,
    const float* __restrict__ bk, const float* __restrict__ bv,
    short* __restrict__ Kp, short* __restrict__ Vt)
{
    __shared__ short lA[2][32 * 64];
    __shared__ short lB[2][128 * 64];

    const int y = blockIdx.y;
    const float* A = y ? vin : kin;
    const short* WT = y ? WvT : WkT;
    const float* bias = y ? bv : bk;

    const int tid  = threadIdx.x;
    const int lane = tid & 63;
    const int wid  = tid >> 6;
    const int l16  = lane & 15;
    const int quad = lane >> 4;
    const int bm   = blockIdx.x;

    v4f acc[2][2];
#pragma unroll
    for (int i = 0; i < 2; ++i)
#pragma unroll
        for (int j = 0; j < 2; ++j) acc[i][j] = (v4f){0.f, 0.f, 0.f, 0.f};

    const int crow = lane >> 3;
    const int ccol = ((lane & 7) ^ crow) << 3;

    float4 areg[2];

    auto loadA = [&](int kt) {
#pragma unroll
        for (int r = 0; r < 2; ++r) {
            const int f4 = tid + 256 * r;
            const int row = f4 >> 4;
            const int q4 = f4 & 15;
            areg[r] = *reinterpret_cast<const float4*>(
                A + (size_t)(bm * 32 + row) * DMODEL + kt * 64 + q4 * 4);
        }
    };
    auto writeA = [&](int pb) {
#pragma unroll
        for (int r = 0; r < 2; ++r) {
            const int f4 = tid + 256 * r;
            const int row = f4 >> 4;
            const int q4 = f4 & 15;
            const int gran = q4 >> 1, half = q4 & 1;
            const int scol = ((gran ^ (row & 7)) << 3) + (half << 2);
            s4pack p{f2bs(areg[r].x), f2bs(areg[r].y), f2bs(areg[r].z), f2bs(areg[r].w)};
            *reinterpret_cast<s4pack*>(&lA[pb][row * 64 + scol]) = p;
        }
    };
    auto stageB = [&](int kt, int pb) {
#pragma unroll
        for (int c = wid; c < 16; c += 4)
            gld16(WT + (size_t)(c * 8 + crow) * DMODEL + kt * 64 + ccol, &lB[pb][c * 512]);
    };
    auto compute = [&](int cur) {
#pragma unroll
        for (int kk = 0; kk < 2; ++kk) {
            const int fcol = (((kk << 2) + quad) ^ (l16 & 7)) << 3;
            v8s af[2], bf[2];
#pragma unroll
            for (int i = 0; i < 2; ++i)
                af[i] = *reinterpret_cast<const v8s*>(&lA[cur][(i * 16 + l16) * 64 + fcol]);
#pragma unroll
            for (int j = 0; j < 2; ++j)
                bf[j] = *reinterpret_cast<const v8s*>(&lB[cur][(wid * 32 + j * 16 + l16) * 64 + fcol]);
            __builtin_amdgcn_s_setprio(1);
#pragma unroll
            for (int i = 0; i < 2; ++i)
#pragma unroll
                for (int j = 0; j < 2; ++j)
                    acc[i][j] = __builtin_amdgcn_mfma_f32_16x16x32_bf16(af[i], bf[j], acc[i][j], 0, 0, 0);
            __builtin_amdgcn_s_setprio(0);
        }
    };

    loadA(0);
    writeA(0);
    stageB(0, 0);
    WAIT_VM0_LGKM0();
    BARRIER();
    for (int kt = 0; kt < 12; ++kt) {
        const int cur = kt & 1;
        if (kt < 11) { loadA(kt + 1); stageB(kt + 1, cur ^ 1); }
        compute(cur);
        if (kt < 11) writeA(cur ^ 1);
        WAIT_VM0_LGKM0();
        BARRIER();
    }

#pragma unroll
    for (int i = 0; i < 2; ++i)
#pragma unroll
        for (int j = 0; j < 2; ++j) {
            const int Cl = wid * 32 + j * 16 + l16;
            const float bvv = bias[Cl];
            const int g = Cl >> 6, d = Cl & 63;
#pragma unroll
            for (int reg = 0; reg < 4; ++reg) {
                const int R = bm * 32 + i * 16 + quad * 4 + reg;
                const int b = R >> 11;
                const int s = R & 2047;
                if (y == 0) {
                    Kp[((size_t)(b * GROUPS + g) * SEQ + s) * DK + d] =
                        f2bs(acc[i][j][reg] + bvv);
                } else {
                    const int s2 = (s & ~63) | (s & 0x23) | ((s & 0x0C) << 1) | ((s & 0x10) >> 2);
                    Vt[((size_t)(b * GROUPS + g) * DK + d) * SEQ + s2] =
                        f2bs(acc[i][j][reg] + bvv);
                }
            }
        }
}

// ---------------------------------------------------------------------------
// Flash attention: 512 threads / 8 waves, 16 q-rows per wave (QBLK=128 per
// block unchanged -> no extra K/V re-reads). T14 async-STAGE split + T5.
// grid (16, 12, 4) = 768 blocks; LDS 35.8KB -> 4 blocks/CU; target 24 w/CU.
// ---------------------------------------------------------------------------
__global__ __launch_bounds__(512) void attn_kernel(
    const short* __restrict__ Qp, const short* __restrict__ Kp,
    const short* __restrict__ Vt, short* __restrict__ Oat)
{
    const int LSK = 72;
    const int LSV = 136;
    __shared__ short lK[128 * 72];
    __shared__ short lV[64 * 136];

    const int qt = blockIdx.x, h = blockIdx.y, b = blockIdx.z;
    const int g = h & 1;
    const int tid  = threadIdx.x;
    const int lane = tid & 63;
    const int wid  = tid >> 6;       // 0..7
    const int l16  = lane & 15;
    const int quad = lane >> 4;

    v8s qf[2];
    {
        const size_t qbase =
            ((size_t)(b * HEADS + h) * SEQ + qt * 128 + wid * 16 + l16) * DK;
        qf[0] = *reinterpret_cast<const v8s*>(Qp + qbase + quad * 8);
        qf[1] = *reinterpret_cast<const v8s*>(Qp + qbase + quad * 8 + 32);
    }

    const size_t kbase = (size_t)(b * GROUPS + g) * SEQ * DK;
    const size_t vbase = (size_t)(b * GROUPS + g) * DK * SEQ;

    const short one = (short)0x3F80;
    const v8s ones8 = {one, one, one, one, one, one, one, one};

    v4f oacc[5];
#pragma unroll
    for (int n = 0; n < 5; ++n) oacc[n] = (v4f){0.f, 0.f, 0.f, 0.f};

    v8s kreg[2], vreg[2];

    auto issue_loads = [&](int kt) {
#pragma unroll
        for (int r = 0; r < 2; ++r) {
            const int idx = tid + 512 * r;
            const int rowK = idx >> 3, cK = (idx & 7) << 3;
            kreg[r] = *reinterpret_cast<const v8s*>(
                Kp + kbase + (size_t)(kt * 128 + rowK) * DK + cK);
            const int rowV = idx >> 4, cV = (idx & 15) << 3;
            vreg[r] = *reinterpret_cast<const v8s*>(
                Vt + vbase + (size_t)rowV * SEQ + kt * 128 + cV);
        }
    };
    auto write_lds = [&]() {
#pragma unroll
        for (int r = 0; r < 2; ++r) {
            const int idx = tid + 512 * r;
            const int rowK = idx >> 3, cK = (idx & 7) << 3;
            *reinterpret_cast<v8s*>(&lK[rowK * LSK + cK]) = kreg[r];
            const int rowV = idx >> 4, cV = (idx & 15) << 3;
            *reinterpret_cast<v8s*>(&lV[rowV * LSV + cV]) = vreg[r];
        }
    };

    issue_loads(0);
    for (int kt = 0; kt < 16; ++kt) {
        if (kt) BARRIER();            // readers of tile kt-1 done (no vmcnt drain)
        write_lds();                  // consumes kreg/vreg (compiler vmcnt waits)
        if (kt < 15) issue_loads(kt + 1);  // in flight across barrier + compute
        WAIT_LGKM0();                 // ds_writes visible before barrier
        BARRIER();

#pragma unroll
        for (int kt2 = 0; kt2 < 2; ++kt2) {
            v4s pp[4];
#pragma unroll
            for (int j = 0; j < 4; ++j) {
                const v8s kf0 = *reinterpret_cast<const v8s*>(
                    &lK[(kt2 * 64 + j * 16 + l16) * LSK + quad * 8]);
                const v8s kf1 = *reinterpret_cast<const v8s*>(
                    &lK[(kt2 * 64 + j * 16 + l16) * LSK + quad * 8 + 32]);
                v4f z = (v4f){0.f, 0.f, 0.f, 0.f};
                __builtin_amdgcn_s_setprio(1);
                z = __builtin_amdgcn_mfma_f32_16x16x32_bf16(kf0, qf[0], z, 0, 0, 0);
                z = __builtin_amdgcn_mfma_f32_16x16x32_bf16(kf1, qf[1], z, 0, 0, 0);
                __builtin_amdgcn_s_setprio(0);
                v4s p;
#pragma unroll
                for (int reg = 0; reg < 4; ++reg) p[reg] = f2bs(fast_exp2(z[reg]));
                pp[j] = p;
            }

#pragma unroll
            for (int cj = 0; cj < 2; ++cj) {
                const v8s pf = __builtin_shufflevector(pp[2 * cj], pp[2 * cj + 1],
                                                       0, 1, 2, 3, 4, 5, 6, 7);
                __builtin_amdgcn_s_setprio(1);
#pragma unroll
                for (int n = 0; n < 4; ++n) {
                    const v8s vf = *reinterpret_cast<const v8s*>(
                        &lV[(n * 16 + l16) * LSV + kt2 * 64 + cj * 32 + quad * 8]);
                    oacc[n] = __builtin_amdgcn_mfma_f32_16x16x32_bf16(pf, vf, oacc[n], 0, 0, 0);
                }
                oacc[4] = __builtin_amdgcn_mfma_f32_16x16x32_bf16(pf, ones8, oacc[4], 0, 0, 0);
                __builtin_amdgcn_s_setprio(0);
            }
        }
    }

    {
        float rdiv[4];
#pragma unroll
        for (int reg = 0; reg < 4; ++reg)
            rdiv[reg] = __builtin_amdgcn_rcpf(oacc[4][reg]);
#pragma unroll
        for (int n = 0; n < 4; ++n)
#pragma unroll
            for (int reg = 0; reg < 4; ++reg) {
                const int qrow = qt * 128 + wid * 16 + quad * 4 + reg;
                Oat[(size_t)(b * SEQ + qrow) * DMODEL + h * 64 + n * 16 + l16] =
                    f2bs(oacc[n][reg] * rdiv[reg]);
            }
    }
}

// ---------------------------------------------------------------------------
// Output GEMM: BM=64, BN=128, BK=64, dbuf, 2-phase, swizzle. grid (128, 6)
// = 768 blocks = 3/CU. out fp32. (Unchanged control from round 1.)
// ---------------------------------------------------------------------------
__global__ __launch_bounds__(256) void out_gemm(
    const short* __restrict__ A, const short* __restrict__ WT,
    const float* __restrict__ bias, float* __restrict__ out)
{
    __shared__ short lA[2][64 * 64];
    __shared__ short lB[2][128 * 64];

    const int tid  = threadIdx.x;
    const int lane = tid & 63;
    const int wid  = tid >> 6;
    const int l16  = lane & 15;
    const int quad = lane >> 4;
    const int wm   = wid & 1;
    const int wn   = wid >> 1;
    const int bm   = blockIdx.x;
    const int bn   = blockIdx.y;

    v4f acc[2][4];
#pragma unroll
    for (int i = 0; i < 2; ++i)
#pragma unroll
        for (int j = 0; j < 4; ++j) acc[i][j] = (v4f){0.f, 0.f, 0.f, 0.f};

    const int crow = lane >> 3;
    const int ccol = ((lane & 7) ^ crow) << 3;
    const short* Abase = A + (size_t)bm * 64 * DMODEL;
    const short* Bbase = WT + (size_t)bn * 128 * DMODEL;

    auto stage = [&](int kt, int pb) {
#pragma unroll
        for (int c = wid; c < 8; c += 4)
            gld16(Abase + (size_t)(c * 8 + crow) * DMODEL + kt * 64 + ccol, &lA[pb][c * 512]);
#pragma unroll
        for (int c = wid; c < 16; c += 4)
            gld16(Bbase + (size_t)(c * 8 + crow) * DMODEL + kt * 64 + ccol, &lB[pb][c * 512]);
    };
    auto compute = [&](int cur) {
#pragma unroll
        for (int kk = 0; kk < 2; ++kk) {
            const int fcol = (((kk << 2) + quad) ^ (l16 & 7)) << 3;
            v8s af[2], bf[4];
#pragma unroll
            for (int i = 0; i < 2; ++i)
                af[i] = *reinterpret_cast<const v8s*>(&lA[cur][(wm * 32 + i * 16 + l16) * 64 + fcol]);
#pragma unroll
            for (int j = 0; j < 4; ++j)
                bf[j] = *reinterpret_cast<const v8s*>(&lB[cur][(wn * 64 + j * 16 + l16) * 64 + fcol]);
            __builtin_amdgcn_s_setprio(1);
#pragma unroll
            for (int i = 0; i < 2; ++i)
#pragma unroll
                for (int j = 0; j < 4; ++j)
                    acc[i][j] = __builtin_amdgcn_mfma_f32_16x16x32_bf16(af[i], bf[j], acc[i][j], 0, 0, 0);
            __builtin_amdgcn_s_setprio(0);
        }
    };

    stage(0, 0);
    WAIT_VM0();
    BARRIER();
    for (int kt = 0; kt < 12; ++kt) {
        const int cur = kt & 1;
        if (kt < 11) stage(kt + 1, cur ^ 1);
        compute(cur);
        WAIT_VM0();
        BARRIER();
    }

#pragma unroll
    for (int i = 0; i < 2; ++i)
#pragma unroll
        for (int j = 0; j < 4; ++j) {
            const int C = bn * 128 + wn * 64 + j * 16 + l16;
            const float bv = bias[C];
#pragma unroll
            for (int reg = 0; reg < 4; ++reg) {
                const int R = bm * 64 + wm * 32 + i * 16 + quad * 4 + reg;
                out[(size_t)R * DMODEL + C] = acc[i][j][reg] + bv;
            }
        }
}

extern "C" void kernel_launch(void* const* d_in, const int* in_sizes, int n_in,
                              void* d_out, int out_size, void* d_ws, size_t ws_size,
                              hipStream_t stream) {
    const float* q  = (const float*)d_in[0];
    const float* k  = (const float*)d_in[1];
    const float* v  = (const float*)d_in[2];
    const float* Wq = (const float*)d_in[3];
    const float* bq = (const float*)d_in[4];
    const float* Wk = (const float*)d_in[5];
    const float* bk = (const float*)d_in[6];
    const float* Wv = (const float*)d_in[7];
    const float* bv = (const float*)d_in[8];
    const float* Wo = (const float*)d_in[9];
    const float* bo = (const float*)d_in[10];

    short* WqT = (short*)d_ws;                              // 589824
    short* WkT = WqT + 589824;                              // 98304
    short* WvT = WkT + 98304;                               // 98304
    short* WoT = WvT + 98304;                               // 589824
    short* qbf = WoT + 589824;                              // 6291456
    short* Qp  = qbf + 6291456;                             // [b,h,s,d]  6291456
    short* Kp  = Qp + (size_t)BS * HEADS * SEQ * DK;        // [b,g,s,d]  1048576
    short* Vt  = Kp + (size_t)BS * GROUPS * SEQ * DK;       // [b,g,d,s_perm] 1048576
    short* Oat = Vt + (size_t)BS * GROUPS * SEQ * DK;       // [b,s,h*d]  6291456

    convert_q<<<1536, 256, 0, stream>>>(q, qbf);
    wtrans_all<<<dim3(24, 24, 4), 256, 0, stream>>>(Wq, Wk, Wv, Wo, WqT, WkT, WvT, WoT);
    proj_q<<<dim3(128, 6), 256, 0, stream>>>(qbf, WqT, bq, Qp);
    proj_kv<<<dim3(256, 2), 256, 0, stream>>>(k, v, WkT, WvT, bk, bv, Kp, Vt);
    attn_kernel<<<dim3(16, HEADS, BS), 512, 0, stream>>>(Qp, Kp, Vt, Oat);
    out_gemm<<<dim3(128, 6), 256, 0, stream>>>(Oat, WoT, bo, (float*)d_out);
}